// Round 14
// baseline (469.964 us; speedup 1.0000x reference)
//
#include <hip/hip_runtime.h>
#include <cmath>

// PhaseAwareClassifier on MI355X — R14: transient Cr (no persistence).
// R12/R13 post-mortem: 640-thr block => >=3 waves/SIMD => ~168-reg hard cap;
// 64 acc + 40 persistent A-frags + ~84 transients > cap => forced spill
// (121MB scratch) regardless of array vs named form. R14: Cr is loaded per
// kt as a TRANSIENT from global (same addresses every step -> L1/L2-hot;
// 2 loads/kt/wave). Ci negated on the A-side (2 bneg/kt, not 4/n4).
// Register demand ~= 64 acc + 40 transient -> no spill.
// Math identical to R8..R13 (absmax 7.8e-3 validated).

#define NSTEPS  10
#define INJ_ST  4

typedef __bf16 bf16x8 __attribute__((ext_vector_type(8)));
typedef __bf16 bf16x4 __attribute__((ext_vector_type(4)));
typedef short  short8 __attribute__((ext_vector_type(8)));
typedef float  f32x4  __attribute__((ext_vector_type(4)));

// workspace layout (float offsets)
#define WS_MAX    0          // 1      enc_max (uint-ordered float)
#define WS_ENERGY 64         // 1280   energy[b][10]
#define WS_GSP    2048       // 160    gsp2[j] = -2*log2(e)*softplus(gain)
#define WS_CONN   4096       // 2 bf16 matrices [20][160][8] chunked: Cr, Ci
#define WS_INJ    32768      // 100352 inj[b][49][16] = px * 1.02/enc_max

__global__ void k_init(float* ws) {
    int i = blockIdx.x * 256 + threadIdx.x;
    if (i == 0) ws[WS_MAX] = 0.f;
    if (i < 1280) ws[WS_ENERGY + i] = 0.f;
}

__global__ void k_max(const float* __restrict__ img, float* ws, int n) {
    __shared__ float sm[256];
    float v = 0.f;
    for (int i = blockIdx.x * blockDim.x + threadIdx.x; i < n; i += gridDim.x * blockDim.x)
        v = fmaxf(v, fabsf(img[i]));
    sm[threadIdx.x] = v;
    __syncthreads();
    for (int s = 128; s > 0; s >>= 1) {
        if (threadIdx.x < s) sm[threadIdx.x] = fmaxf(sm[threadIdx.x], sm[threadIdx.x + s]);
        __syncthreads();
    }
    if (threadIdx.x == 0)
        atomicMax((unsigned int*)(ws + WS_MAX), __float_as_uint(sm[0]));
}

__global__ void k_prep(const float* __restrict__ img,
                       const float* __restrict__ cr, const float* __restrict__ ci,
                       const float* __restrict__ phase, const float* __restrict__ gain,
                       float* ws) {
    int i = blockIdx.x * 256 + threadIdx.x;
    __bf16* Cb = (__bf16*)(ws + WS_CONN);
    if (i < 25600) {                       // (m=j row, k=s col) of A
        int m = i / 160, k = i % 160;
        float vr = 0.f, vi = 0.f;
        if (m < 131 && k < 131) {
            float a = cr[k * 131 + m], b = ci[k * 131 + m];
            float ph = phase[m];
            float cp = cosf(ph), sp = sinf(ph);
            vr = a * cp - b * sp;
            vi = a * sp + b * cp;
        }
        int ca = ((k >> 3) * 160 + m) * 8 + (k & 7);   // chunked addr
        Cb[ca]         = (__bf16)vr;
        Cb[25600 + ca] = (__bf16)vi;
    } else if (i < 25760) {
        int j = i - 25600;
        float g = 0.f;
        if (j < 131) {
            float x = gain[j];
            g = (x > 20.f) ? x : log1pf(expf(x));  // softplus
        }
        ws[WS_GSP + j] = g * -2.8853901817f;        // -2*log2(e)*g
    } else if (i < 25760 + 128 * 49 * 16) {
        int q = i - 25760;
        int m = q & 15, jj = (q >> 4) % 49, b = q / (49 * 16);
        int u = m >> 2, v2 = m & 3, pi = jj / 7, pj = jj % 7;
        float px = img[b * 784 + (pi * 4 + u) * 28 + (pj * 4 + v2)];
        float mx = ws[WS_MAX];
        float sc = (mx > 1e-8f) ? (1.02f / mx) : 1.02f;   // 0.85*4*0.3
        ws[WS_INJ + q] = px * sc;
    }
}

static __device__ __forceinline__ f32x4 MF(bf16x8 a, bf16x8 b, f32x4 c) {
    return __builtin_amdgcn_mfma_f32_16x16x32_bf16(a, b, c, 0, 0, 0);
}
static __device__ __forceinline__ bf16x8 bneg(bf16x8 a) {
    short8 t = __builtin_bit_cast(short8, a) ^ (short8)(short)0x8000;
    return __builtin_bit_cast(bf16x8, t);
}

__global__ __launch_bounds__(640, 1)
void k_main(const float* __restrict__ ws, float* __restrict__ energy) {
    __shared__ __bf16 OB[2][20 * 128 * 8];         // 81,920 B: Or, Oi chunked
    __shared__ __bf16 CiL[20 * 160 * 8];           // 51,200 B: Ci chunked
    __shared__ float scrE[10 * 128];               //  5,120 B  -> 138,240 total
    const int tid  = threadIdx.x;
    const int lane = tid & 63;
    const int ln15 = lane & 15;
    const int quad = lane >> 4;
    const int wv   = __builtin_amdgcn_readfirstlane(tid >> 6);  // 0..9
    const int mg   = wv >> 1;                       // 0..4: M-tiles 2mg, 2mg+1
    const int ng   = wv & 1;                        // N-tiles 4ng..4ng+3
    const int b    = blockIdx.x >> 3;               // 8 blocks per image
    const int m    = ln15;

    const __bf16* __restrict__ Crg = (const __bf16*)(ws + WS_CONN);
    const __bf16* __restrict__ Cig = Crg + 25600;
    const float* __restrict__ gsp2 = ws + WS_GSP;
    const float* __restrict__ injb = ws + WS_INJ;

    __bf16* __restrict__ OBr = &OB[0][0];
    __bf16* __restrict__ OBi = &OB[1][0];

    // per-ntile encoding weight
    float wls[4];
#pragma unroll
    for (int q = 0; q < 4; ++q) {
        int l = (blockIdx.x * 8 + 4 * ng + q) & 63;
        wls[q] = 1.0f - fabsf((float)l - 32.0f) * (1.0f / 64.0f);
    }

    // stage Ci -> LDS; zero O-state
    {
        const int4* src = (const int4*)Cig;
        int4* dst = (int4*)CiL;
        for (int i = tid; i < 3200; i += 640) dst[i] = src[i];
        int4* ob = (int4*)&OB[0][0];
        int4 z = {0, 0, 0, 0};
        for (int i = tid; i < 5120; i += 640) ob[i] = z;
    }

    f32x4 accr[8], acci[8];                         // acc == 4 * field
#pragma unroll
    for (int p = 0; p < 8; ++p) { accr[p] = (f32x4)0.f; acci[p] = (f32x4)0.f; }

    // injection (rows j<49 -> only waves with mg<2; constant indices)
    auto inj_add = [&]() {
        if (mg < 2) {
#pragma unroll
            for (int p = 0; p < 8; ++p) {
                const int j0 = (2 * mg + (p >> 2)) * 16 + quad * 4;
#pragma unroll
                for (int r = 0; r < 4; ++r) {
                    int j = j0 + r;
                    if (j < 49) accr[p][r] += injb[(b * 49 + j) * 16 + m] * wls[p & 3];
                }
            }
        }
    };

    // epilogue: out = tanh-rescale(0.25*acc) -> bf16 chunked LDS write
    auto epilogue = [&](bool last) {
#pragma unroll
        for (int p = 0; p < 8; ++p) {
            const int j0 = (2 * mg + (p >> 2)) * 16 + quad * 4;
            const int n  = (4 * ng + (p & 3)) * 16 + ln15;
            float g2[4];
            *(float4*)g2 = *(const float4*)(gsp2 + j0);
            bf16x4 pr, pi;
#pragma unroll
            for (int r = 0; r < 4; ++r) {
                float fr = accr[p][r] * 0.25f;
                float fi = acci[p][r] * 0.25f;
                float mag2 = fmaf(fr, fr, fmaf(fi, fi, 1e-8f));
                float rmag = __builtin_amdgcn_rsqf(mag2);       // 1/mag
                float magv = mag2 * rmag;                       // mag
                float e = __builtin_amdgcn_exp2f(g2[r] * magv); // exp(-2*g*mag)
                float th = 1.0f - 2.0f * e * __builtin_amdgcn_rcpf(1.0f + e);
                float scv = th * rmag;                          // tanh/mag
                float orv = fr * scv, oiv = fi * scv;
                pr[r] = (__bf16)orv; pi[r] = (__bf16)oiv;
                if (last) {
                    int j = j0 + r;
                    if (j >= 121 && j <= 130)
                        scrE[(j - 121) * 128 + n] = orv * orv + oiv * oiv;
                }
            }
            const int off = ((j0 >> 3) * 128 + n) * 8 + (j0 & 7);
            *(bf16x4*)(OBr + off) = pr;
            *(bf16x4*)(OBi + off) = pi;
        }
    };

    __syncthreads();
    inj_add();                                      // t = 0 (out is zero)
    epilogue(false);
    __syncthreads();

    for (int t = 1; t < NSTEPS; ++t) {
#pragma unroll
        for (int p = 0; p < 8; ++p) { accr[p] *= 0.85f; acci[p] *= 0.85f; }
        if (t < INJ_ST) inj_add();

        // ---- MFMA: G += C * O (complex bf16; Cr transient from global/L2,
        //      Ci and O from LDS; -Ci applied on the A side) ----
#pragma unroll
        for (int kt = 0; kt < 5; ++kt) {
            const int kch = kt * 4 + quad;
            bf16x8 ar0 = *(const bf16x8*)(Crg +
                ((kch * 160) + (2 * mg + 0) * 16 + ln15) * 8);
            bf16x8 ar1 = *(const bf16x8*)(Crg +
                ((kch * 160) + (2 * mg + 1) * 16 + ln15) * 8);
            bf16x8 ai0 = *(const bf16x8*)(CiL +
                ((kch * 160) + (2 * mg + 0) * 16 + ln15) * 8);
            bf16x8 ai1 = *(const bf16x8*)(CiL +
                ((kch * 160) + (2 * mg + 1) * 16 + ln15) * 8);
            bf16x8 nai0 = bneg(ai0);
            bf16x8 nai1 = bneg(ai1);
#pragma unroll
            for (int n4 = 0; n4 < 4; ++n4) {
                const int boff = (kch * 128 + (4 * ng + n4) * 16 + ln15) * 8;
                bf16x8 b_r = *(const bf16x8*)(OBr + boff);
                bf16x8 b_i = *(const bf16x8*)(OBi + boff);
                accr[n4]     = MF(ar0,  b_r, accr[n4]);     // G_r += Cr*Or
                accr[n4]     = MF(nai0, b_i, accr[n4]);     // G_r -= Ci*Oi
                acci[n4]     = MF(ar0,  b_i, acci[n4]);     // G_i += Cr*Oi
                acci[n4]     = MF(ai0,  b_r, acci[n4]);     // G_i += Ci*Or
                accr[4 + n4] = MF(ar1,  b_r, accr[4 + n4]);
                accr[4 + n4] = MF(nai1, b_i, accr[4 + n4]);
                acci[4 + n4] = MF(ar1,  b_i, acci[4 + n4]);
                acci[4 + n4] = MF(ai1,  b_r, acci[4 + n4]);
            }
        }
        __syncthreads();   // all reads of OB done
        epilogue(t == NSTEPS - 1);
        __syncthreads();   // OB ready for next step
    }

    // ---- energy: scrE[10][128] holds exact fp32 |out|^2 ----
    if (tid < 10) {
        float ssum = 0.f;
        for (int cc = 0; cc < 128; ++cc) ssum += scrE[tid * 128 + cc];
        atomicAdd(energy + b * 10 + tid, ssum);
    }
}

__global__ void k_readout(const float* __restrict__ ws,
                          const float* __restrict__ W,
                          const float* __restrict__ bias,
                          float* __restrict__ out) {
    int i = blockIdx.x * 256 + threadIdx.x;
    if (i < 1280) {
        int b = i / 10, o = i % 10;
        float s = bias[o];
#pragma unroll
        for (int f = 0; f < 10; ++f) {
            float feat = log1pf(ws[WS_ENERGY + b * 10 + f] + 1e-8f);
            s = fmaf(feat, W[o * 10 + f], s);
        }
        out[i] = s;
    }
}

extern "C" void kernel_launch(void* const* d_in, const int* in_sizes, int n_in,
                              void* d_out, int out_size, void* d_ws, size_t ws_size,
                              hipStream_t stream) {
    const float* images = (const float*)d_in[0];
    const float* conn_r = (const float*)d_in[1];
    const float* conn_i = (const float*)d_in[2];
    const float* phase  = (const float*)d_in[3];
    const float* gain   = (const float*)d_in[4];
    const float* W      = (const float*)d_in[5];
    const float* bias   = (const float*)d_in[6];
    float* ws  = (float*)d_ws;
    float* out = (float*)d_out;

    hipLaunchKernelGGL(k_init, dim3(6), dim3(256), 0, stream, ws);
    hipLaunchKernelGGL(k_max, dim3(98), dim3(256), 0, stream, images, ws, 128 * 28 * 28);
    hipLaunchKernelGGL(k_prep, dim3(493), dim3(256), 0, stream,
                       images, conn_r, conn_i, phase, gain, ws);
    hipLaunchKernelGGL(k_main, dim3(1024), dim3(640), 0, stream, ws, ws + WS_ENERGY);
    hipLaunchKernelGGL(k_readout, dim3(5), dim3(256), 0, stream, ws, W, bias, out);
}

// Round 15
// 394.876 us; speedup vs baseline: 1.1902x; 1.1902x over previous
//
#include <hip/hip_runtime.h>
#include <cmath>

// PhaseAwareClassifier on MI355X — R15: R14 + kt-loop unroll(1).
// R12-R14 post-mortem: full unroll of the kt loop let the scheduler hoist
// ~60 b128 loads per step -> ~240 regs of in-flight results -> scratch
// spills (105-152MB WRITE). R8/R9, which were spill-free, used unroll(1).
// VGPR_Count=84 is arch-only; the 64 acc regs live as AGPRs (unified file).
// R15 = R14 structure (N=128, 10 waves, Ci in LDS, Cr transient L2, -Ci on
// A side) with #pragma unroll 1 on kt. Math identical (absmax 7.8e-3).

#define NSTEPS  10
#define INJ_ST  4

typedef __bf16 bf16x8 __attribute__((ext_vector_type(8)));
typedef __bf16 bf16x4 __attribute__((ext_vector_type(4)));
typedef short  short8 __attribute__((ext_vector_type(8)));
typedef float  f32x4  __attribute__((ext_vector_type(4)));

// workspace layout (float offsets)
#define WS_MAX    0          // 1      enc_max (uint-ordered float)
#define WS_ENERGY 64         // 1280   energy[b][10]
#define WS_GSP    2048       // 160    gsp2[j] = -2*log2(e)*softplus(gain)
#define WS_CONN   4096       // 2 bf16 matrices [20][160][8] chunked: Cr, Ci
#define WS_INJ    32768      // 100352 inj[b][49][16] = px * 1.02/enc_max

__global__ void k_init(float* ws) {
    int i = blockIdx.x * 256 + threadIdx.x;
    if (i == 0) ws[WS_MAX] = 0.f;
    if (i < 1280) ws[WS_ENERGY + i] = 0.f;
}

__global__ void k_max(const float* __restrict__ img, float* ws, int n) {
    __shared__ float sm[256];
    float v = 0.f;
    for (int i = blockIdx.x * blockDim.x + threadIdx.x; i < n; i += gridDim.x * blockDim.x)
        v = fmaxf(v, fabsf(img[i]));
    sm[threadIdx.x] = v;
    __syncthreads();
    for (int s = 128; s > 0; s >>= 1) {
        if (threadIdx.x < s) sm[threadIdx.x] = fmaxf(sm[threadIdx.x], sm[threadIdx.x + s]);
        __syncthreads();
    }
    if (threadIdx.x == 0)
        atomicMax((unsigned int*)(ws + WS_MAX), __float_as_uint(sm[0]));
}

__global__ void k_prep(const float* __restrict__ img,
                       const float* __restrict__ cr, const float* __restrict__ ci,
                       const float* __restrict__ phase, const float* __restrict__ gain,
                       float* ws) {
    int i = blockIdx.x * 256 + threadIdx.x;
    __bf16* Cb = (__bf16*)(ws + WS_CONN);
    if (i < 25600) {                       // (m=j row, k=s col) of A
        int m = i / 160, k = i % 160;
        float vr = 0.f, vi = 0.f;
        if (m < 131 && k < 131) {
            float a = cr[k * 131 + m], b = ci[k * 131 + m];
            float ph = phase[m];
            float cp = cosf(ph), sp = sinf(ph);
            vr = a * cp - b * sp;
            vi = a * sp + b * cp;
        }
        int ca = ((k >> 3) * 160 + m) * 8 + (k & 7);   // chunked addr
        Cb[ca]         = (__bf16)vr;
        Cb[25600 + ca] = (__bf16)vi;
    } else if (i < 25760) {
        int j = i - 25600;
        float g = 0.f;
        if (j < 131) {
            float x = gain[j];
            g = (x > 20.f) ? x : log1pf(expf(x));  // softplus
        }
        ws[WS_GSP + j] = g * -2.8853901817f;        // -2*log2(e)*g
    } else if (i < 25760 + 128 * 49 * 16) {
        int q = i - 25760;
        int m = q & 15, jj = (q >> 4) % 49, b = q / (49 * 16);
        int u = m >> 2, v2 = m & 3, pi = jj / 7, pj = jj % 7;
        float px = img[b * 784 + (pi * 4 + u) * 28 + (pj * 4 + v2)];
        float mx = ws[WS_MAX];
        float sc = (mx > 1e-8f) ? (1.02f / mx) : 1.02f;   // 0.85*4*0.3
        ws[WS_INJ + q] = px * sc;
    }
}

static __device__ __forceinline__ f32x4 MF(bf16x8 a, bf16x8 b, f32x4 c) {
    return __builtin_amdgcn_mfma_f32_16x16x32_bf16(a, b, c, 0, 0, 0);
}
static __device__ __forceinline__ bf16x8 bneg(bf16x8 a) {
    short8 t = __builtin_bit_cast(short8, a) ^ (short8)(short)0x8000;
    return __builtin_bit_cast(bf16x8, t);
}

__global__ __launch_bounds__(640, 1)
void k_main(const float* __restrict__ ws, float* __restrict__ energy) {
    __shared__ __bf16 OB[2][20 * 128 * 8];         // 81,920 B: Or, Oi chunked
    __shared__ __bf16 CiL[20 * 160 * 8];           // 51,200 B: Ci chunked
    __shared__ float scrE[10 * 128];               //  5,120 B  -> 138,240 total
    const int tid  = threadIdx.x;
    const int lane = tid & 63;
    const int ln15 = lane & 15;
    const int quad = lane >> 4;
    const int wv   = __builtin_amdgcn_readfirstlane(tid >> 6);  // 0..9
    const int mg   = wv >> 1;                       // 0..4: M-tiles 2mg, 2mg+1
    const int ng   = wv & 1;                        // N-tiles 4ng..4ng+3
    const int b    = blockIdx.x >> 3;               // 8 blocks per image
    const int m    = ln15;

    const __bf16* __restrict__ Crg = (const __bf16*)(ws + WS_CONN);
    const __bf16* __restrict__ Cig = Crg + 25600;
    const float* __restrict__ gsp2 = ws + WS_GSP;
    const float* __restrict__ injb = ws + WS_INJ;

    __bf16* __restrict__ OBr = &OB[0][0];
    __bf16* __restrict__ OBi = &OB[1][0];

    // per-ntile encoding weight
    float wls[4];
#pragma unroll
    for (int q = 0; q < 4; ++q) {
        int l = (blockIdx.x * 8 + 4 * ng + q) & 63;
        wls[q] = 1.0f - fabsf((float)l - 32.0f) * (1.0f / 64.0f);
    }

    // stage Ci -> LDS; zero O-state
    {
        const int4* src = (const int4*)Cig;
        int4* dst = (int4*)CiL;
        for (int i = tid; i < 3200; i += 640) dst[i] = src[i];
        int4* ob = (int4*)&OB[0][0];
        int4 z = {0, 0, 0, 0};
        for (int i = tid; i < 5120; i += 640) ob[i] = z;
    }

    f32x4 accr[8], acci[8];                         // acc == 4 * field
#pragma unroll
    for (int p = 0; p < 8; ++p) { accr[p] = (f32x4)0.f; acci[p] = (f32x4)0.f; }

    // injection (rows j<49 -> only waves with mg<2; constant indices)
    auto inj_add = [&]() {
        if (mg < 2) {
#pragma unroll
            for (int p = 0; p < 8; ++p) {
                const int j0 = (2 * mg + (p >> 2)) * 16 + quad * 4;
#pragma unroll
                for (int r = 0; r < 4; ++r) {
                    int j = j0 + r;
                    if (j < 49) accr[p][r] += injb[(b * 49 + j) * 16 + m] * wls[p & 3];
                }
            }
        }
    };

    // epilogue: out = tanh-rescale(0.25*acc) -> bf16 chunked LDS write
    auto epilogue = [&](bool last) {
#pragma unroll
        for (int p = 0; p < 8; ++p) {
            const int j0 = (2 * mg + (p >> 2)) * 16 + quad * 4;
            const int n  = (4 * ng + (p & 3)) * 16 + ln15;
            float g2[4];
            *(float4*)g2 = *(const float4*)(gsp2 + j0);
            bf16x4 pr, pi;
#pragma unroll
            for (int r = 0; r < 4; ++r) {
                float fr = accr[p][r] * 0.25f;
                float fi = acci[p][r] * 0.25f;
                float mag2 = fmaf(fr, fr, fmaf(fi, fi, 1e-8f));
                float rmag = __builtin_amdgcn_rsqf(mag2);       // 1/mag
                float magv = mag2 * rmag;                       // mag
                float e = __builtin_amdgcn_exp2f(g2[r] * magv); // exp(-2*g*mag)
                float th = 1.0f - 2.0f * e * __builtin_amdgcn_rcpf(1.0f + e);
                float scv = th * rmag;                          // tanh/mag
                float orv = fr * scv, oiv = fi * scv;
                pr[r] = (__bf16)orv; pi[r] = (__bf16)oiv;
                if (last) {
                    int j = j0 + r;
                    if (j >= 121 && j <= 130)
                        scrE[(j - 121) * 128 + n] = orv * orv + oiv * oiv;
                }
            }
            const int off = ((j0 >> 3) * 128 + n) * 8 + (j0 & 7);
            *(bf16x4*)(OBr + off) = pr;
            *(bf16x4*)(OBi + off) = pi;
        }
    };

    __syncthreads();
    inj_add();                                      // t = 0 (out is zero)
    epilogue(false);
    __syncthreads();

    for (int t = 1; t < NSTEPS; ++t) {
#pragma unroll
        for (int p = 0; p < 8; ++p) { accr[p] *= 0.85f; acci[p] *= 0.85f; }
        if (t < INJ_ST) inj_add();

        // ---- MFMA: G += C * O (complex bf16; Cr transient from global/L2,
        //      Ci and O from LDS; -Ci applied on the A side) ----
        // unroll(1): one kt = 12 loads + 32 MFMAs; full unroll hoists ~60
        // loads and forces scratch spills (R12-R14's 105-152MB WRITE_SIZE).
#pragma unroll 1
        for (int kt = 0; kt < 5; ++kt) {
            const int kch = kt * 4 + quad;
            bf16x8 ar0 = *(const bf16x8*)(Crg +
                ((kch * 160) + (2 * mg + 0) * 16 + ln15) * 8);
            bf16x8 ar1 = *(const bf16x8*)(Crg +
                ((kch * 160) + (2 * mg + 1) * 16 + ln15) * 8);
            bf16x8 ai0 = *(const bf16x8*)(CiL +
                ((kch * 160) + (2 * mg + 0) * 16 + ln15) * 8);
            bf16x8 ai1 = *(const bf16x8*)(CiL +
                ((kch * 160) + (2 * mg + 1) * 16 + ln15) * 8);
            bf16x8 nai0 = bneg(ai0);
            bf16x8 nai1 = bneg(ai1);
#pragma unroll
            for (int n4 = 0; n4 < 4; ++n4) {
                const int boff = (kch * 128 + (4 * ng + n4) * 16 + ln15) * 8;
                bf16x8 b_r = *(const bf16x8*)(OBr + boff);
                bf16x8 b_i = *(const bf16x8*)(OBi + boff);
                accr[n4]     = MF(ar0,  b_r, accr[n4]);     // G_r += Cr*Or
                accr[n4]     = MF(nai0, b_i, accr[n4]);     // G_r -= Ci*Oi
                acci[n4]     = MF(ar0,  b_i, acci[n4]);     // G_i += Cr*Oi
                acci[n4]     = MF(ai0,  b_r, acci[n4]);     // G_i += Ci*Or
                accr[4 + n4] = MF(ar1,  b_r, accr[4 + n4]);
                accr[4 + n4] = MF(nai1, b_i, accr[4 + n4]);
                acci[4 + n4] = MF(ar1,  b_i, acci[4 + n4]);
                acci[4 + n4] = MF(ai1,  b_r, acci[4 + n4]);
            }
        }
        __syncthreads();   // all reads of OB done
        epilogue(t == NSTEPS - 1);
        __syncthreads();   // OB ready for next step
    }

    // ---- energy: scrE[10][128] holds exact fp32 |out|^2 ----
    if (tid < 10) {
        float ssum = 0.f;
        for (int cc = 0; cc < 128; ++cc) ssum += scrE[tid * 128 + cc];
        atomicAdd(energy + b * 10 + tid, ssum);
    }
}

__global__ void k_readout(const float* __restrict__ ws,
                          const float* __restrict__ W,
                          const float* __restrict__ bias,
                          float* __restrict__ out) {
    int i = blockIdx.x * 256 + threadIdx.x;
    if (i < 1280) {
        int b = i / 10, o = i % 10;
        float s = bias[o];
#pragma unroll
        for (int f = 0; f < 10; ++f) {
            float feat = log1pf(ws[WS_ENERGY + b * 10 + f] + 1e-8f);
            s = fmaf(feat, W[o * 10 + f], s);
        }
        out[i] = s;
    }
}

extern "C" void kernel_launch(void* const* d_in, const int* in_sizes, int n_in,
                              void* d_out, int out_size, void* d_ws, size_t ws_size,
                              hipStream_t stream) {
    const float* images = (const float*)d_in[0];
    const float* conn_r = (const float*)d_in[1];
    const float* conn_i = (const float*)d_in[2];
    const float* phase  = (const float*)d_in[3];
    const float* gain   = (const float*)d_in[4];
    const float* W      = (const float*)d_in[5];
    const float* bias   = (const float*)d_in[6];
    float* ws  = (float*)d_ws;
    float* out = (float*)d_out;

    hipLaunchKernelGGL(k_init, dim3(6), dim3(256), 0, stream, ws);
    hipLaunchKernelGGL(k_max, dim3(98), dim3(256), 0, stream, images, ws, 128 * 28 * 28);
    hipLaunchKernelGGL(k_prep, dim3(493), dim3(256), 0, stream,
                       images, conn_r, conn_i, phase, gain, ws);
    hipLaunchKernelGGL(k_main, dim3(1024), dim3(640), 0, stream, ws, ws + WS_ENERGY);
    hipLaunchKernelGGL(k_readout, dim3(5), dim3(256), 0, stream, ws, W, bias, out);
}

// Round 16
// 347.825 us; speedup vs baseline: 1.3512x; 1.1353x over previous
//
#include <hip/hip_runtime.h>
#include <cmath>

// PhaseAwareClassifier on MI355X — R16: M=144 (9 tiles), 12-wave block.
// R15 established: unroll(1) on kt prevents load-hoist spills (WRITE 3.9KB).
// R16 removes the M-padding waste (160->144; ceil(131/16)=9 tiles) and
// raises occupancy: 768-thr block = 12 waves in a 3(mg) x 4(ng) grid, each
// wave 3 M-tiles x 2 N-tiles = 6 positions (acc 48 regs < R15's 64).
// MFMA/A-traffic -10%, epilogue -25%/wave, waves/CU 10->12. All loop bounds
// compile-time (R11 lesson). Cr transient from global (L1/L2-hot), Ci in
// LDS, O chunked in LDS. Math identical to R8..R15 (absmax 7.8e-3).

#define NSTEPS  10
#define INJ_ST  4
#define MT      144          // padded M (9 tiles of 16)
#define NCH     20           // K chunks of 8 (K=160 = 5 MFMA k-steps of 32)

typedef __bf16 bf16x8 __attribute__((ext_vector_type(8)));
typedef __bf16 bf16x4 __attribute__((ext_vector_type(4)));
typedef short  short8 __attribute__((ext_vector_type(8)));
typedef float  f32x4  __attribute__((ext_vector_type(4)));

// workspace layout (float offsets)
#define WS_MAX    0          // 1      enc_max (uint-ordered float)
#define WS_ENERGY 64         // 1280   energy[b][10]
#define WS_GSP    2048       // 144    gsp2[j] = -2*log2(e)*softplus(gain)
#define WS_CONN   4096       // 2 bf16 mats [20][144][8] chunked: Cr, Ci (23040 fl)
#define WS_INJ    32768      // 100352 inj[b][49][16] = px * 1.02/enc_max

__global__ void k_init(float* ws) {
    int i = blockIdx.x * 256 + threadIdx.x;
    if (i == 0) ws[WS_MAX] = 0.f;
    if (i < 1280) ws[WS_ENERGY + i] = 0.f;
}

__global__ void k_max(const float* __restrict__ img, float* ws, int n) {
    __shared__ float sm[256];
    float v = 0.f;
    for (int i = blockIdx.x * blockDim.x + threadIdx.x; i < n; i += gridDim.x * blockDim.x)
        v = fmaxf(v, fabsf(img[i]));
    sm[threadIdx.x] = v;
    __syncthreads();
    for (int s = 128; s > 0; s >>= 1) {
        if (threadIdx.x < s) sm[threadIdx.x] = fmaxf(sm[threadIdx.x], sm[threadIdx.x + s]);
        __syncthreads();
    }
    if (threadIdx.x == 0)
        atomicMax((unsigned int*)(ws + WS_MAX), __float_as_uint(sm[0]));
}

__global__ void k_prep(const float* __restrict__ img,
                       const float* __restrict__ cr, const float* __restrict__ ci,
                       const float* __restrict__ phase, const float* __restrict__ gain,
                       float* ws) {
    int i = blockIdx.x * 256 + threadIdx.x;
    __bf16* Cb = (__bf16*)(ws + WS_CONN);
    const int NCE = MT * 160;              // 23040 (m,k) pairs
    if (i < NCE) {
        int m = i / 160, k = i % 160;
        float vr = 0.f, vi = 0.f;
        if (m < 131 && k < 131) {
            float a = cr[k * 131 + m], b = ci[k * 131 + m];
            float ph = phase[m];
            float cp = cosf(ph), sp = sinf(ph);
            vr = a * cp - b * sp;
            vi = a * sp + b * cp;
        }
        int ca = ((k >> 3) * MT + m) * 8 + (k & 7);    // chunked addr
        Cb[ca]       = (__bf16)vr;
        Cb[NCE + ca] = (__bf16)vi;
    } else if (i < NCE + MT) {
        int j = i - NCE;
        float g = 0.f;
        if (j < 131) {
            float x = gain[j];
            g = (x > 20.f) ? x : log1pf(expf(x));  // softplus
        }
        ws[WS_GSP + j] = g * -2.8853901817f;        // -2*log2(e)*g
    } else if (i < NCE + MT + 128 * 49 * 16) {
        int q = i - NCE - MT;
        int m = q & 15, jj = (q >> 4) % 49, b = q / (49 * 16);
        int u = m >> 2, v2 = m & 3, pi = jj / 7, pj = jj % 7;
        float px = img[b * 784 + (pi * 4 + u) * 28 + (pj * 4 + v2)];
        float mx = ws[WS_MAX];
        float sc = (mx > 1e-8f) ? (1.02f / mx) : 1.02f;   // 0.85*4*0.3
        ws[WS_INJ + q] = px * sc;
    }
}

static __device__ __forceinline__ f32x4 MF(bf16x8 a, bf16x8 b, f32x4 c) {
    return __builtin_amdgcn_mfma_f32_16x16x32_bf16(a, b, c, 0, 0, 0);
}
static __device__ __forceinline__ bf16x8 bneg(bf16x8 a) {
    short8 t = __builtin_bit_cast(short8, a) ^ (short8)(short)0x8000;
    return __builtin_bit_cast(bf16x8, t);
}

__global__ __launch_bounds__(768, 1)
void k_main(const float* __restrict__ ws, float* __restrict__ energy) {
    __shared__ __bf16 OB[2][NCH * 128 * 8];        // 81,920 B: Or, Oi chunked
    __shared__ __bf16 CiL[NCH * MT * 8];           // 46,080 B: Ci chunked
    __shared__ float scrE[10 * 128];               //  5,120 B -> 133,120 total
    const int tid  = threadIdx.x;
    const int lane = tid & 63;
    const int ln15 = lane & 15;
    const int quad = lane >> 4;
    const int wv   = __builtin_amdgcn_readfirstlane(tid >> 6);  // 0..11
    const int mg   = wv >> 2;                       // 0..2: M-tiles 3mg..3mg+2
    const int ng   = wv & 3;                        // N-tiles 2ng, 2ng+1
    const int b    = blockIdx.x >> 3;               // 8 blocks per image
    const int m    = ln15;

    const __bf16* __restrict__ Crg = (const __bf16*)(ws + WS_CONN);
    const __bf16* __restrict__ Cig = Crg + MT * 160;
    const float* __restrict__ gsp2 = ws + WS_GSP;
    const float* __restrict__ injb = ws + WS_INJ;

    __bf16* __restrict__ OBr = &OB[0][0];
    __bf16* __restrict__ OBi = &OB[1][0];

    // per-position encoding weight (pn = 0,1)
    float wls[2];
#pragma unroll
    for (int q = 0; q < 2; ++q) {
        int l = ((blockIdx.x & 7) * 8 + 2 * ng + q) & 63;
        wls[q] = 1.0f - fabsf((float)l - 32.0f) * (1.0f / 64.0f);
    }

    // stage Ci -> LDS; zero O-state
    {
        const int4* src = (const int4*)Cig;
        int4* dst = (int4*)CiL;
        for (int i = tid; i < 2880; i += 768) dst[i] = src[i];
        int4* ob = (int4*)&OB[0][0];
        int4 z = {0, 0, 0, 0};
        for (int i = tid; i < 5120; i += 768) ob[i] = z;
    }

    f32x4 accr[6], acci[6];                         // acc == 4*field; p=pm*2+pn
#pragma unroll
    for (int p = 0; p < 6; ++p) { accr[p] = (f32x4)0.f; acci[p] = (f32x4)0.f; }

    // injection (rows j<49 -> mg 0 fully, mg 1 only j=48; constant indices)
    auto inj_add = [&]() {
        if (mg < 2) {
#pragma unroll
            for (int p = 0; p < 6; ++p) {
                const int j0 = (3 * mg + (p >> 1)) * 16 + quad * 4;
#pragma unroll
                for (int r = 0; r < 4; ++r) {
                    int j = j0 + r;
                    if (j < 49) accr[p][r] += injb[(b * 49 + j) * 16 + m] * wls[p & 1];
                }
            }
        }
    };

    // epilogue: out = tanh-rescale(0.25*acc) -> bf16 chunked LDS write
    auto epilogue = [&](bool last) {
#pragma unroll
        for (int p = 0; p < 6; ++p) {
            const int j0 = (3 * mg + (p >> 1)) * 16 + quad * 4;
            const int n  = (2 * ng + (p & 1)) * 16 + ln15;
            float g2[4];
            *(float4*)g2 = *(const float4*)(gsp2 + j0);
            bf16x4 pr, pi;
#pragma unroll
            for (int r = 0; r < 4; ++r) {
                float fr = accr[p][r] * 0.25f;
                float fi = acci[p][r] * 0.25f;
                float mag2 = fmaf(fr, fr, fmaf(fi, fi, 1e-8f));
                float rmag = __builtin_amdgcn_rsqf(mag2);       // 1/mag
                float magv = mag2 * rmag;                       // mag
                float e = __builtin_amdgcn_exp2f(g2[r] * magv); // exp(-2*g*mag)
                float th = 1.0f - 2.0f * e * __builtin_amdgcn_rcpf(1.0f + e);
                float scv = th * rmag;                          // tanh/mag
                float orv = fr * scv, oiv = fi * scv;
                pr[r] = (__bf16)orv; pi[r] = (__bf16)oiv;
                if (last) {
                    int j = j0 + r;
                    if (j >= 121 && j <= 130)
                        scrE[(j - 121) * 128 + n] = orv * orv + oiv * oiv;
                }
            }
            const int off = ((j0 >> 3) * 128 + n) * 8 + (j0 & 7);
            *(bf16x4*)(OBr + off) = pr;
            *(bf16x4*)(OBi + off) = pi;
        }
    };

    __syncthreads();
    inj_add();                                      // t = 0 (out is zero)
    epilogue(false);
    __syncthreads();

    for (int t = 1; t < NSTEPS; ++t) {
#pragma unroll
        for (int p = 0; p < 6; ++p) { accr[p] *= 0.85f; acci[p] *= 0.85f; }
        if (t < INJ_ST) inj_add();

        // ---- MFMA: G += C * O (complex bf16; Cr transient from global/L2,
        //      Ci and O from LDS; -Ci applied on the A side) ----
        // unroll(1): one kt = 11 loads + 24 MFMAs; full unroll hoists loads
        // and forces scratch spills (R12-R14: 105-152MB WRITE_SIZE).
#pragma unroll 1
        for (int kt = 0; kt < 5; ++kt) {
            const int kch = kt * 4 + quad;
            const int abase = kch * MT + 3 * mg * 16 + ln15;
            bf16x8 ar0 = *(const bf16x8*)(Crg + (abase)      * 8);
            bf16x8 ar1 = *(const bf16x8*)(Crg + (abase + 16) * 8);
            bf16x8 ar2 = *(const bf16x8*)(Crg + (abase + 32) * 8);
            bf16x8 ai0 = *(const bf16x8*)(CiL + (abase)      * 8);
            bf16x8 ai1 = *(const bf16x8*)(CiL + (abase + 16) * 8);
            bf16x8 ai2 = *(const bf16x8*)(CiL + (abase + 32) * 8);
            bf16x8 nai0 = bneg(ai0);
            bf16x8 nai1 = bneg(ai1);
            bf16x8 nai2 = bneg(ai2);
#pragma unroll
            for (int pn = 0; pn < 2; ++pn) {
                const int boff = (kch * 128 + (2 * ng + pn) * 16 + ln15) * 8;
                bf16x8 b_r = *(const bf16x8*)(OBr + boff);
                bf16x8 b_i = *(const bf16x8*)(OBi + boff);
                accr[pn]     = MF(ar0,  b_r, accr[pn]);
                accr[pn]     = MF(nai0, b_i, accr[pn]);
                acci[pn]     = MF(ar0,  b_i, acci[pn]);
                acci[pn]     = MF(ai0,  b_r, acci[pn]);
                accr[2 + pn] = MF(ar1,  b_r, accr[2 + pn]);
                accr[2 + pn] = MF(nai1, b_i, accr[2 + pn]);
                acci[2 + pn] = MF(ar1,  b_i, acci[2 + pn]);
                acci[2 + pn] = MF(ai1,  b_r, acci[2 + pn]);
                accr[4 + pn] = MF(ar2,  b_r, accr[4 + pn]);
                accr[4 + pn] = MF(nai2, b_i, accr[4 + pn]);
                acci[4 + pn] = MF(ar2,  b_i, acci[4 + pn]);
                acci[4 + pn] = MF(ai2,  b_r, acci[4 + pn]);
            }
        }
        __syncthreads();   // all reads of OB done
        epilogue(t == NSTEPS - 1);
        __syncthreads();   // OB ready for next step
    }

    // ---- energy: scrE[10][128] holds exact fp32 |out|^2 ----
    if (tid < 10) {
        float ssum = 0.f;
        for (int cc = 0; cc < 128; ++cc) ssum += scrE[tid * 128 + cc];
        atomicAdd(energy + b * 10 + tid, ssum);
    }
}

__global__ void k_readout(const float* __restrict__ ws,
                          const float* __restrict__ W,
                          const float* __restrict__ bias,
                          float* __restrict__ out) {
    int i = blockIdx.x * 256 + threadIdx.x;
    if (i < 1280) {
        int b = i / 10, o = i % 10;
        float s = bias[o];
#pragma unroll
        for (int f = 0; f < 10; ++f) {
            float feat = log1pf(ws[WS_ENERGY + b * 10 + f] + 1e-8f);
            s = fmaf(feat, W[o * 10 + f], s);
        }
        out[i] = s;
    }
}

extern "C" void kernel_launch(void* const* d_in, const int* in_sizes, int n_in,
                              void* d_out, int out_size, void* d_ws, size_t ws_size,
                              hipStream_t stream) {
    const float* images = (const float*)d_in[0];
    const float* conn_r = (const float*)d_in[1];
    const float* conn_i = (const float*)d_in[2];
    const float* phase  = (const float*)d_in[3];
    const float* gain   = (const float*)d_in[4];
    const float* W      = (const float*)d_in[5];
    const float* bias   = (const float*)d_in[6];
    float* ws  = (float*)d_ws;
    float* out = (float*)d_out;

    hipLaunchKernelGGL(k_init, dim3(6), dim3(256), 0, stream, ws);
    hipLaunchKernelGGL(k_max, dim3(98), dim3(256), 0, stream, images, ws, 128 * 28 * 28);
    hipLaunchKernelGGL(k_prep, dim3(484), dim3(256), 0, stream,
                       images, conn_r, conn_i, phase, gain, ws);
    hipLaunchKernelGGL(k_main, dim3(1024), dim3(768), 0, stream, ws, ws + WS_ENERGY);
    hipLaunchKernelGGL(k_readout, dim3(5), dim3(256), 0, stream, ws, W, bias, out);
}

// Round 17
// 322.271 us; speedup vs baseline: 1.4583x; 1.0793x over previous
//
#include <hip/hip_runtime.h>
#include <cmath>

// PhaseAwareClassifier on MI355X — R17: all operands in LDS, 18-chunk trick.
// R16 post-mortem: in-loop global Cr loads (46KB > 32KB L1) expose ~200-300
// cyc L2 latency per kt with only 3 waves/SIMD to hide it. Fix: conn cols
// k>=136 and O rows j>=136 are identically zero, so A and B need only 18 of
// 20 k-chunks in LDS; chunk 18/19 reads remap to chunk 17 (zeros) via min().
// LDS: OB 73,728 + CrL 41,472 + CiL 41,472 = 156,672 B (scrE aliases CrL,
// dead after last MFMA). MFMA loop touches LDS only. bneg on B-side (2/kt).
// Discipline kept: unroll(1) on kt (R15), constant bounds (R11), no forced
// reg caps (R2/R6). Math identical to R8..R16 (absmax 7.8e-3).

#define NSTEPS  10
#define INJ_ST  4
#define MT      144          // padded M (9 tiles of 16)

typedef __bf16 bf16x8 __attribute__((ext_vector_type(8)));
typedef __bf16 bf16x4 __attribute__((ext_vector_type(4)));
typedef short  short8 __attribute__((ext_vector_type(8)));
typedef float  f32x4  __attribute__((ext_vector_type(4)));

// workspace layout (float offsets)
#define WS_MAX    0          // 1      enc_max (uint-ordered float)
#define WS_ENERGY 64         // 1280   energy[b][10]
#define WS_GSP    2048       // 144    gsp2[j] = -2*log2(e)*softplus(gain)
#define WS_CONN   4096       // 2 bf16 mats [20][144][8] chunked: Cr, Ci
#define WS_INJ    32768      // 100352 inj[b][49][16] = px * 1.02/enc_max

__global__ void k_init(float* ws) {
    int i = blockIdx.x * 256 + threadIdx.x;
    if (i == 0) ws[WS_MAX] = 0.f;
    if (i < 1280) ws[WS_ENERGY + i] = 0.f;
}

__global__ void k_max(const float* __restrict__ img, float* ws, int n) {
    __shared__ float sm[256];
    float v = 0.f;
    for (int i = blockIdx.x * blockDim.x + threadIdx.x; i < n; i += gridDim.x * blockDim.x)
        v = fmaxf(v, fabsf(img[i]));
    sm[threadIdx.x] = v;
    __syncthreads();
    for (int s = 128; s > 0; s >>= 1) {
        if (threadIdx.x < s) sm[threadIdx.x] = fmaxf(sm[threadIdx.x], sm[threadIdx.x + s]);
        __syncthreads();
    }
    if (threadIdx.x == 0)
        atomicMax((unsigned int*)(ws + WS_MAX), __float_as_uint(sm[0]));
}

__global__ void k_prep(const float* __restrict__ img,
                       const float* __restrict__ cr, const float* __restrict__ ci,
                       const float* __restrict__ phase, const float* __restrict__ gain,
                       float* ws) {
    int i = blockIdx.x * 256 + threadIdx.x;
    __bf16* Cb = (__bf16*)(ws + WS_CONN);
    const int NCE = MT * 160;              // 23040 (m,k) pairs
    if (i < NCE) {
        int m = i / 160, k = i % 160;
        float vr = 0.f, vi = 0.f;
        if (m < 131 && k < 131) {
            float a = cr[k * 131 + m], b = ci[k * 131 + m];
            float ph = phase[m];
            float cp = cosf(ph), sp = sinf(ph);
            vr = a * cp - b * sp;
            vi = a * sp + b * cp;
        }
        int ca = ((k >> 3) * MT + m) * 8 + (k & 7);    // chunked addr
        Cb[ca]       = (__bf16)vr;
        Cb[NCE + ca] = (__bf16)vi;
    } else if (i < NCE + MT) {
        int j = i - NCE;
        float g = 0.f;
        if (j < 131) {
            float x = gain[j];
            g = (x > 20.f) ? x : log1pf(expf(x));  // softplus
        }
        ws[WS_GSP + j] = g * -2.8853901817f;        // -2*log2(e)*g
    } else if (i < NCE + MT + 128 * 49 * 16) {
        int q = i - NCE - MT;
        int m = q & 15, jj = (q >> 4) % 49, b = q / (49 * 16);
        int u = m >> 2, v2 = m & 3, pi = jj / 7, pj = jj % 7;
        float px = img[b * 784 + (pi * 4 + u) * 28 + (pj * 4 + v2)];
        float mx = ws[WS_MAX];
        float sc = (mx > 1e-8f) ? (1.02f / mx) : 1.02f;   // 0.85*4*0.3
        ws[WS_INJ + q] = px * sc;
    }
}

static __device__ __forceinline__ f32x4 MF(bf16x8 a, bf16x8 b, f32x4 c) {
    return __builtin_amdgcn_mfma_f32_16x16x32_bf16(a, b, c, 0, 0, 0);
}
static __device__ __forceinline__ bf16x8 bneg(bf16x8 a) {
    short8 t = __builtin_bit_cast(short8, a) ^ (short8)(short)0x8000;
    return __builtin_bit_cast(bf16x8, t);
}

__global__ __launch_bounds__(768, 1)
void k_main(const float* __restrict__ ws, float* __restrict__ energy) {
    __shared__ __bf16 OB[2][18 * 128 * 8];         // 73,728 B: Or, Oi (18 ch)
    __shared__ __bf16 CrL[18 * MT * 8];            // 41,472 B: Cr (18 ch)
    __shared__ __bf16 CiL[18 * MT * 8];            // 41,472 B: Ci (18 ch)
    // total 156,672 B -> 1 block/CU. scrE aliases CrL (dead after last MFMA).
    const int tid  = threadIdx.x;
    const int lane = tid & 63;
    const int ln15 = lane & 15;
    const int quad = lane >> 4;
    const int wv   = __builtin_amdgcn_readfirstlane(tid >> 6);  // 0..11
    const int mg   = wv >> 2;                       // 0..2: M-tiles 3mg..3mg+2
    const int ng   = wv & 3;                        // N-tiles 2ng, 2ng+1
    const int b    = blockIdx.x >> 3;               // 8 blocks per image
    const int m    = ln15;

    const float* __restrict__ gsp2 = ws + WS_GSP;
    const float* __restrict__ injb = ws + WS_INJ;

    __bf16* __restrict__ OBr = &OB[0][0];
    __bf16* __restrict__ OBi = &OB[1][0];
    float* scrE = (float*)CrL;                      // alias: used only at end

    // per-position encoding weight (pn = 0,1)
    float wls[2];
#pragma unroll
    for (int q = 0; q < 2; ++q) {
        int l = ((blockIdx.x & 7) * 8 + 2 * ng + q) & 63;
        wls[q] = 1.0f - fabsf((float)l - 32.0f) * (1.0f / 64.0f);
    }

    // stage Cr, Ci (chunks 0..17) -> LDS; zero O-state
    {
        const int4* srcR = (const int4*)(ws + WS_CONN);
        const int4* srcI = (const int4*)(ws + WS_CONN + (MT * 160 / 2)); // +20ch
        int4* dstR = (int4*)CrL;
        int4* dstI = (int4*)CiL;
        for (int i = tid; i < 2592; i += 768) { dstR[i] = srcR[i]; dstI[i] = srcI[i]; }
        int4* ob = (int4*)&OB[0][0];
        int4 z = {0, 0, 0, 0};
        for (int i = tid; i < 4608; i += 768) ob[i] = z;
    }

    f32x4 accr[6], acci[6];                         // acc == 4*field; p=pm*2+pn
#pragma unroll
    for (int p = 0; p < 6; ++p) { accr[p] = (f32x4)0.f; acci[p] = (f32x4)0.f; }

    // injection (rows j<49 -> mg 0 fully, mg 1 only j=48; constant indices)
    auto inj_add = [&]() {
        if (mg < 2) {
#pragma unroll
            for (int p = 0; p < 6; ++p) {
                const int j0 = (3 * mg + (p >> 1)) * 16 + quad * 4;
#pragma unroll
                for (int r = 0; r < 4; ++r) {
                    int j = j0 + r;
                    if (j < 49) accr[p][r] += injb[(b * 49 + j) * 16 + m] * wls[p & 1];
                }
            }
        }
    };

    // epilogue: out = tanh-rescale(0.25*acc) -> bf16 chunked LDS write
    auto epilogue = [&](bool last) {
#pragma unroll
        for (int p = 0; p < 6; ++p) {
            const int j0 = (3 * mg + (p >> 1)) * 16 + quad * 4;
            const int n  = (2 * ng + (p & 1)) * 16 + ln15;
            float g2[4];
            *(float4*)g2 = *(const float4*)(gsp2 + j0);
            bf16x4 pr, pi;
#pragma unroll
            for (int r = 0; r < 4; ++r) {
                float fr = accr[p][r] * 0.25f;
                float fi = acci[p][r] * 0.25f;
                float mag2 = fmaf(fr, fr, fmaf(fi, fi, 1e-8f));
                float rmag = __builtin_amdgcn_rsqf(mag2);       // 1/mag
                float magv = mag2 * rmag;                       // mag
                float e = __builtin_amdgcn_exp2f(g2[r] * magv); // exp(-2*g*mag)
                float th = 1.0f - 2.0f * e * __builtin_amdgcn_rcpf(1.0f + e);
                float scv = th * rmag;                          // tanh/mag
                float orv = fr * scv, oiv = fi * scv;
                pr[r] = (__bf16)orv; pi[r] = (__bf16)oiv;
                if (last) {
                    int j = j0 + r;
                    if (j >= 121 && j <= 130)
                        scrE[(j - 121) * 128 + n] = orv * orv + oiv * oiv;
                }
            }
            const int off = ((j0 >> 3) * 128 + n) * 8 + (j0 & 7);
            *(bf16x4*)(OBr + off) = pr;
            *(bf16x4*)(OBi + off) = pi;
        }
    };

    __syncthreads();
    inj_add();                                      // t = 0 (out is zero)
    epilogue(false);
    __syncthreads();

    for (int t = 1; t < NSTEPS; ++t) {
#pragma unroll
        for (int p = 0; p < 6; ++p) { accr[p] *= 0.85f; acci[p] *= 0.85f; }
        if (t < INJ_ST) inj_add();

        // ---- MFMA: G += C * O (complex bf16; ALL operands from LDS).
        // kch 18,19 (k>=144) remap to chunk 17 (k 136..143 = guaranteed
        // zeros for both conn and O) -> 18 stored chunks suffice.
        // unroll(1): full unroll hoists loads -> scratch (R12-R14 lesson).
#pragma unroll 1
        for (int kt = 0; kt < 5; ++kt) {
            const int kch = kt * 4 + quad;
            const int rk  = (kch > 17) ? 17 : kch;
            const int abase = (rk * MT + 48 * mg + ln15) * 8;
            bf16x8 ar0 = *(const bf16x8*)(CrL + abase);
            bf16x8 ar1 = *(const bf16x8*)(CrL + abase + 128);
            bf16x8 ar2 = *(const bf16x8*)(CrL + abase + 256);
            bf16x8 ai0 = *(const bf16x8*)(CiL + abase);
            bf16x8 ai1 = *(const bf16x8*)(CiL + abase + 128);
            bf16x8 ai2 = *(const bf16x8*)(CiL + abase + 256);
#pragma unroll
            for (int pn = 0; pn < 2; ++pn) {
                const int boff = (rk * 128 + (2 * ng + pn) * 16 + ln15) * 8;
                bf16x8 b_r  = *(const bf16x8*)(OBr + boff);
                bf16x8 b_i  = *(const bf16x8*)(OBi + boff);
                bf16x8 b_ni = bneg(b_i);
                accr[pn]     = MF(ar0, b_r,  accr[pn]);
                accr[pn]     = MF(ai0, b_ni, accr[pn]);
                acci[pn]     = MF(ar0, b_i,  acci[pn]);
                acci[pn]     = MF(ai0, b_r,  acci[pn]);
                accr[2 + pn] = MF(ar1, b_r,  accr[2 + pn]);
                accr[2 + pn] = MF(ai1, b_ni, accr[2 + pn]);
                acci[2 + pn] = MF(ar1, b_i,  acci[2 + pn]);
                acci[2 + pn] = MF(ai1, b_r,  acci[2 + pn]);
                accr[4 + pn] = MF(ar2, b_r,  accr[4 + pn]);
                accr[4 + pn] = MF(ai2, b_ni, accr[4 + pn]);
                acci[4 + pn] = MF(ar2, b_i,  acci[4 + pn]);
                acci[4 + pn] = MF(ai2, b_r,  acci[4 + pn]);
            }
        }
        __syncthreads();   // all reads of OB/CrL/CiL done
        epilogue(t == NSTEPS - 1);
        __syncthreads();   // OB (and scrE on last) ready
    }

    // ---- energy: scrE[10][128] (aliasing CrL) holds exact fp32 |out|^2 ----
    if (tid < 10) {
        float ssum = 0.f;
        for (int cc = 0; cc < 128; ++cc) ssum += scrE[tid * 128 + cc];
        atomicAdd(energy + b * 10 + tid, ssum);
    }
}

__global__ void k_readout(const float* __restrict__ ws,
                          const float* __restrict__ W,
                          const float* __restrict__ bias,
                          float* __restrict__ out) {
    int i = blockIdx.x * 256 + threadIdx.x;
    if (i < 1280) {
        int b = i / 10, o = i % 10;
        float s = bias[o];
#pragma unroll
        for (int f = 0; f < 10; ++f) {
            float feat = log1pf(ws[WS_ENERGY + b * 10 + f] + 1e-8f);
            s = fmaf(feat, W[o * 10 + f], s);
        }
        out[i] = s;
    }
}

extern "C" void kernel_launch(void* const* d_in, const int* in_sizes, int n_in,
                              void* d_out, int out_size, void* d_ws, size_t ws_size,
                              hipStream_t stream) {
    const float* images = (const float*)d_in[0];
    const float* conn_r = (const float*)d_in[1];
    const float* conn_i = (const float*)d_in[2];
    const float* phase  = (const float*)d_in[3];
    const float* gain   = (const float*)d_in[4];
    const float* W      = (const float*)d_in[5];
    const float* bias   = (const float*)d_in[6];
    float* ws  = (float*)d_ws;
    float* out = (float*)d_out;

    hipLaunchKernelGGL(k_init, dim3(6), dim3(256), 0, stream, ws);
    hipLaunchKernelGGL(k_max, dim3(98), dim3(256), 0, stream, images, ws, 128 * 28 * 28);
    hipLaunchKernelGGL(k_prep, dim3(484), dim3(256), 0, stream,
                       images, conn_r, conn_i, phase, gain, ws);
    hipLaunchKernelGGL(k_main, dim3(1024), dim3(768), 0, stream, ws, ws + WS_ENERGY);
    hipLaunchKernelGGL(k_readout, dim3(5), dim3(256), 0, stream, ws, W, bias, out);
}